// Round 1
// 327.420 us; speedup vs baseline: 1.0103x; 1.0103x over previous
//
#include <hip/hip_runtime.h>
#include <cstddef>

// ---------------- problem constants (match reference) ----------------
#define NB   4
#define NN_  6
#define ND_  41
#define NFH  16
#define NFW  44
#define NC   64
#define NX0_ 200
#define NX1_ 200
#define NXY  (NX0_ * NX1_)                 // 40000
#define NCOL (NB * NN_ * ND_ * NFW)        // 43296 columns (each = 16 vertical pixels)

// 3x3 inverse via adjugate. For these inputs (integer pinhole K, identity
// post_rots) every cofactor/det is exact in f32 and each division correctly
// rounded -> matches numpy's inv bit-for-bit. (Validated rounds 1-2.)
__device__ __forceinline__ void inv3(const float* a, float* inv) {
    float c00 = __fsub_rn(__fmul_rn(a[4], a[8]), __fmul_rn(a[5], a[7]));
    float c01 = __fsub_rn(__fmul_rn(a[5], a[6]), __fmul_rn(a[3], a[8]));
    float c02 = __fsub_rn(__fmul_rn(a[3], a[7]), __fmul_rn(a[4], a[6]));
    float det = __fadd_rn(__fadd_rn(__fmul_rn(a[0], c00), __fmul_rn(a[1], c01)),
                          __fmul_rn(a[2], c02));
    inv[0] = __fdiv_rn(c00, det);
    inv[1] = __fdiv_rn(__fsub_rn(__fmul_rn(a[2], a[7]), __fmul_rn(a[1], a[8])), det);
    inv[2] = __fdiv_rn(__fsub_rn(__fmul_rn(a[1], a[5]), __fmul_rn(a[2], a[4])), det);
    inv[3] = __fdiv_rn(c01, det);
    inv[4] = __fdiv_rn(__fsub_rn(__fmul_rn(a[0], a[8]), __fmul_rn(a[2], a[6])), det);
    inv[5] = __fdiv_rn(__fsub_rn(__fmul_rn(a[2], a[3]), __fmul_rn(a[0], a[5])), det);
    inv[6] = __fdiv_rn(c02, det);
    inv[7] = __fdiv_rn(__fsub_rn(__fmul_rn(a[1], a[6]), __fmul_rn(a[0], a[7])), det);
    inv[8] = __fdiv_rn(__fsub_rn(__fmul_rn(a[0], a[4]), __fmul_rn(a[1], a[3])), det);
}

__global__ void setup_kernel(const float* __restrict__ rots,
                             const float* __restrict__ trans,
                             const float* __restrict__ intrins,
                             const float* __restrict__ post_rots,
                             const float* __restrict__ post_trans,
                             float* __restrict__ mats) {
    int t = threadIdx.x;
    if (t >= NB * NN_) return;
    const float* R  = rots      + t * 9;
    const float* K  = intrins   + t * 9;
    const float* PR = post_rots + t * 9;
    float Kinv[9], Pinv[9];
    inv3(K, Kinv);
    inv3(PR, Pinv);
    float* o = mats + t * 24;
    for (int i = 0; i < 3; ++i)
        for (int k = 0; k < 3; ++k) {
            float s = __fmul_rn(R[i * 3 + 0], Kinv[0 * 3 + k]);
            s = __fadd_rn(s, __fmul_rn(R[i * 3 + 1], Kinv[1 * 3 + k]));
            s = __fadd_rn(s, __fmul_rn(R[i * 3 + 2], Kinv[2 * 3 + k]));
            o[i * 3 + k] = s;
        }
    for (int i = 0; i < 9; ++i) o[9 + i] = Pinv[i];
    o[18] = trans[t * 3 + 0];
    o[19] = trans[t * 3 + 1];
    o[20] = trans[t * 3 + 2];
    o[21] = post_trans[t * 3 + 0];
    o[22] = post_trans[t * 3 + 1];
    o[23] = post_trans[t * 3 + 2];
}

// Fire-and-forget hardware FP32 atomic add (no return value, no CAS loop).
// HIP's atomicAdd(float*) may lower to a global_load+cmpswap retry loop,
// which is a dependent ~1200-cycle round-trip chain per channel. The
// no-return global_atomic_add_f32 has no dependency: issue and retire.
__device__ __forceinline__ void hw_fadd(float* p, float v) {
    asm volatile("global_atomic_add_f32 %0, %1, off" : : "v"(p), "v"(v) : "memory");
}

// Voxel flat index (b*NXY + i0*NX1 + i1) for point (b,n,d,h,w), or -1.
// Numerics IDENTICAL to the passing rounds: _rn intrinsics only (no fma
// contraction), f64 linspace semantics for u, trunc-toward-zero.
__device__ __forceinline__ int compute_idx(int b, int n, int d, int h, int w,
                                           const float* __restrict__ mats) {
    const float* mp = mats + (b * NN_ + n) * 24;

    float u   = (w == NFW - 1) ? 703.0f : (float)((double)w * (703.0 / 43.0));
    float v   = __fmul_rn((float)h, 17.0f);   // 255/15 == 17 exactly
    float dep = (float)(4 + d);               // arange(4,45,1): exact ints

    float f0 = __fsub_rn(u, mp[21]);
    float f1 = __fsub_rn(v, mp[22]);
    float f2 = __fsub_rn(dep, mp[23]);

    float q0 = __fadd_rn(__fadd_rn(__fmul_rn(mp[9],  f0), __fmul_rn(mp[10], f1)), __fmul_rn(mp[11], f2));
    float q1 = __fadd_rn(__fadd_rn(__fmul_rn(mp[12], f0), __fmul_rn(mp[13], f1)), __fmul_rn(mp[14], f2));
    float q2 = __fadd_rn(__fadd_rn(__fmul_rn(mp[15], f0), __fmul_rn(mp[16], f1)), __fmul_rn(mp[17], f2));

    float r0 = __fmul_rn(q0, q2);
    float r1 = __fmul_rn(q1, q2);

    float g0 = __fadd_rn(__fadd_rn(__fadd_rn(__fmul_rn(mp[0], r0), __fmul_rn(mp[1], r1)), __fmul_rn(mp[2], q2)), mp[18]);
    float g1 = __fadd_rn(__fadd_rn(__fadd_rn(__fmul_rn(mp[3], r0), __fmul_rn(mp[4], r1)), __fmul_rn(mp[5], q2)), mp[19]);
    float g2 = __fadd_rn(__fadd_rn(__fadd_rn(__fmul_rn(mp[6], r0), __fmul_rn(mp[7], r1)), __fmul_rn(mp[8], q2)), mp[20]);

    float s0 = __fdiv_rn(__fsub_rn(g0, -50.0f), 0.5f);
    float s1 = __fdiv_rn(__fsub_rn(g1, -50.0f), 0.5f);
    float s2 = __fdiv_rn(__fsub_rn(g2, -10.0f), 20.0f);
    s0 = fminf(fmaxf(s0, -1e6f), 1e6f);
    s1 = fminf(fmaxf(s1, -1e6f), 1e6f);
    s2 = fminf(fmaxf(s2, -1e6f), 1e6f);
    int i0 = (int)s0;   // trunc toward zero == jnp.trunc().astype(int32)
    int i1 = (int)s1;
    int i2 = (int)s2;
    if (i0 >= 0 && i0 < NX0_ && i1 >= 0 && i1 < NX1_ && i2 >= 0 && i2 < 1)
        return b * NXY + i0 * NX1_ + i1;
    return -1;
}

// One 16-lane group per (b,n,d,w) column; lane l owns channels [4l,4l+4).
// The BEV (i0,i1) cell is exactly h-independent for these inputs (M[0][1] and
// M[1][1] are exactly 0.0f); only z-validity varies with h. So: one uniform
// column-level branch, then 16 UNCONDITIONAL independent float4 loads
// (pipelined by the compiler) and a branchless mask-multiply accumulate —
// which mirrors the reference's `feats * w`. Slow path kept for safety.
__global__ __launch_bounds__(256) void col_pool(const float* __restrict__ x,
                                                const float* __restrict__ mats,
                                                float* __restrict__ out) {
    int cid  = blockIdx.x * 16 + (threadIdx.x >> 4);   // NCOL = 2706*16
    int l    = threadIdx.x & 15;                       // channel quad
    int w = cid % NFW; int t = cid / NFW;
    int d = t % ND_;   t /= ND_;
    int n = t % NN_;   int b = t / NN_;

    int myidx = compute_idx(b, n, d, l, w, mats);

    // gather all 16 per-h indices into registers (no loop-carried deps)
    int idx[16];
    #pragma unroll
    for (int h = 0; h < 16; ++h) idx[h] = __shfl(myidx, h, 16);

    int common = -1;
    bool allsame = true;
    #pragma unroll
    for (int h = 0; h < 16; ++h) {
        if (idx[h] >= 0) {
            if (common < 0) common = idx[h];
            else if (idx[h] != common) allsame = false;
        }
    }
    if (common < 0) return;   // whole column dropped: skip all loads

    const float4* xp = (const float4*)
        (x + (((size_t)((b * NN_ + n) * ND_ + d) * NFH) * NFW + w) * NC) + l;
    const int HSTRIDE = NFW * (NC / 4);   // float4 stride between h rows

    // 16 independent loads — compiler can keep all in flight
    float4 v[16];
    #pragma unroll
    for (int h = 0; h < 16; ++h) v[h] = xp[h * HSTRIDE];

    if (__builtin_expect(allsame, 1)) {
        // branchless mask-multiply accumulate (== reference's feats*w)
        float4 a0 = make_float4(0.f, 0.f, 0.f, 0.f);
        float4 a1 = make_float4(0.f, 0.f, 0.f, 0.f);
        #pragma unroll
        for (int h = 0; h < 16; h += 2) {
            float m0 = (idx[h]     >= 0) ? 1.0f : 0.0f;
            float m1 = (idx[h + 1] >= 0) ? 1.0f : 0.0f;
            a0.x += v[h].x * m0;     a0.y += v[h].y * m0;
            a0.z += v[h].z * m0;     a0.w += v[h].w * m0;
            a1.x += v[h + 1].x * m1; a1.y += v[h + 1].y * m1;
            a1.z += v[h + 1].z * m1; a1.w += v[h + 1].w * m1;
        }
        a0.x += a1.x; a0.y += a1.y; a0.z += a1.z; a0.w += a1.w;
        int bb = common / NXY, xy = common % NXY;
        float* o = out + ((size_t)(bb * NC + l * 4)) * NXY + xy;
        hw_fadd(o,           a0.x);
        hw_fadd(o + NXY,     a0.y);
        hw_fadd(o + 2 * NXY, a0.z);
        hw_fadd(o + 3 * NXY, a0.w);
    } else {
        // safety net (provably unreachable for these inputs)
        #pragma unroll
        for (int h = 0; h < 16; ++h) {
            if (idx[h] >= 0) {
                int bb = idx[h] / NXY, xy = idx[h] % NXY;
                float* o = out + ((size_t)(bb * NC + l * 4)) * NXY + xy;
                hw_fadd(o,           v[h].x);
                hw_fadd(o + NXY,     v[h].y);
                hw_fadd(o + 2 * NXY, v[h].z);
                hw_fadd(o + 3 * NXY, v[h].w);
            }
        }
    }
}

extern "C" void kernel_launch(void* const* d_in, const int* in_sizes, int n_in,
                              void* d_out, int out_size, void* d_ws, size_t ws_size,
                              hipStream_t stream) {
    (void)in_sizes; (void)n_in; (void)out_size; (void)ws_size;
    const float* x          = (const float*)d_in[0];
    const float* rots       = (const float*)d_in[1];
    const float* trans      = (const float*)d_in[2];
    const float* intrins    = (const float*)d_in[3];
    const float* post_rots  = (const float*)d_in[4];
    const float* post_trans = (const float*)d_in[5];
    float* out  = (float*)d_out;
    float* mats = (float*)d_ws;   // 576 floats

    setup_kernel<<<1, 32, 0, stream>>>(rots, trans, intrins, post_rots, post_trans, mats);
    // out is re-poisoned to 0xAA before every timed launch -> zero it each call
    hipMemsetAsync(out, 0, (size_t)NB * NC * NXY * sizeof(float), stream);
    col_pool<<<NCOL / 16, 256, 0, stream>>>(x, mats, out);
}

// Round 2
// 286.010 us; speedup vs baseline: 1.1566x; 1.1448x over previous
//
#include <hip/hip_runtime.h>
#include <cstddef>

// ---------------- problem constants (match reference) ----------------
#define NB   4
#define NN_  6
#define ND_  41
#define NFH  16
#define NFW  44
#define NC   64
#define NX0_ 200
#define NX1_ 200
#define NXY  (NX0_ * NX1_)                 // 40000
#define NCOL (NB * NN_ * ND_ * NFW)        // 43296 columns (each = 16 vertical pixels)

// 3x3 inverse via adjugate. For these inputs (integer pinhole K, identity
// post_rots) every cofactor/det is exact in f32 and each division correctly
// rounded -> matches numpy's inv bit-for-bit. (Validated rounds 1-2.)
__device__ __forceinline__ void inv3(const float* a, float* inv) {
    float c00 = __fsub_rn(__fmul_rn(a[4], a[8]), __fmul_rn(a[5], a[7]));
    float c01 = __fsub_rn(__fmul_rn(a[5], a[6]), __fmul_rn(a[3], a[8]));
    float c02 = __fsub_rn(__fmul_rn(a[3], a[7]), __fmul_rn(a[4], a[6]));
    float det = __fadd_rn(__fadd_rn(__fmul_rn(a[0], c00), __fmul_rn(a[1], c01)),
                          __fmul_rn(a[2], c02));
    inv[0] = __fdiv_rn(c00, det);
    inv[1] = __fdiv_rn(__fsub_rn(__fmul_rn(a[2], a[7]), __fmul_rn(a[1], a[8])), det);
    inv[2] = __fdiv_rn(__fsub_rn(__fmul_rn(a[1], a[5]), __fmul_rn(a[2], a[4])), det);
    inv[3] = __fdiv_rn(c01, det);
    inv[4] = __fdiv_rn(__fsub_rn(__fmul_rn(a[0], a[8]), __fmul_rn(a[2], a[6])), det);
    inv[5] = __fdiv_rn(__fsub_rn(__fmul_rn(a[2], a[3]), __fmul_rn(a[0], a[5])), det);
    inv[6] = __fdiv_rn(c02, det);
    inv[7] = __fdiv_rn(__fsub_rn(__fmul_rn(a[1], a[6]), __fmul_rn(a[0], a[7])), det);
    inv[8] = __fdiv_rn(__fsub_rn(__fmul_rn(a[0], a[4]), __fmul_rn(a[1], a[3])), det);
}

__global__ void setup_kernel(const float* __restrict__ rots,
                             const float* __restrict__ trans,
                             const float* __restrict__ intrins,
                             const float* __restrict__ post_rots,
                             const float* __restrict__ post_trans,
                             float* __restrict__ mats) {
    int t = threadIdx.x;
    if (t >= NB * NN_) return;
    const float* R  = rots      + t * 9;
    const float* K  = intrins   + t * 9;
    const float* PR = post_rots + t * 9;
    float Kinv[9], Pinv[9];
    inv3(K, Kinv);
    inv3(PR, Pinv);
    float* o = mats + t * 24;
    for (int i = 0; i < 3; ++i)
        for (int k = 0; k < 3; ++k) {
            float s = __fmul_rn(R[i * 3 + 0], Kinv[0 * 3 + k]);
            s = __fadd_rn(s, __fmul_rn(R[i * 3 + 1], Kinv[1 * 3 + k]));
            s = __fadd_rn(s, __fmul_rn(R[i * 3 + 2], Kinv[2 * 3 + k]));
            o[i * 3 + k] = s;
        }
    for (int i = 0; i < 9; ++i) o[9 + i] = Pinv[i];
    o[18] = trans[t * 3 + 0];
    o[19] = trans[t * 3 + 1];
    o[20] = trans[t * 3 + 2];
    o[21] = post_trans[t * 3 + 0];
    o[22] = post_trans[t * 3 + 1];
    o[23] = post_trans[t * 3 + 2];
}

// Fire-and-forget hardware FP32 atomic add (no return value -> no CAS loop,
// no dependency on the result). Verified round 1: identical perf to
// atomicAdd, kept for the guaranteed no-return form.
__device__ __forceinline__ void hw_fadd(float* p, float v) {
    asm volatile("global_atomic_add_f32 %0, %1, off" : : "v"(p), "v"(v) : "memory");
}

// Voxel flat index (b*NXY + i0*NX1 + i1) for point (b,n,d,h,w), or -1.
// Numerics IDENTICAL to the passing rounds: _rn intrinsics only (no fma
// contraction), f64 linspace semantics for u, trunc-toward-zero.
__device__ __forceinline__ int compute_idx(int b, int n, int d, int h, int w,
                                           const float* __restrict__ mats) {
    const float* mp = mats + (b * NN_ + n) * 24;

    float u   = (w == NFW - 1) ? 703.0f : (float)((double)w * (703.0 / 43.0));
    float v   = __fmul_rn((float)h, 17.0f);   // 255/15 == 17 exactly
    float dep = (float)(4 + d);               // arange(4,45,1): exact ints

    float f0 = __fsub_rn(u, mp[21]);
    float f1 = __fsub_rn(v, mp[22]);
    float f2 = __fsub_rn(dep, mp[23]);

    float q0 = __fadd_rn(__fadd_rn(__fmul_rn(mp[9],  f0), __fmul_rn(mp[10], f1)), __fmul_rn(mp[11], f2));
    float q1 = __fadd_rn(__fadd_rn(__fmul_rn(mp[12], f0), __fmul_rn(mp[13], f1)), __fmul_rn(mp[14], f2));
    float q2 = __fadd_rn(__fadd_rn(__fmul_rn(mp[15], f0), __fmul_rn(mp[16], f1)), __fmul_rn(mp[17], f2));

    float r0 = __fmul_rn(q0, q2);
    float r1 = __fmul_rn(q1, q2);

    float g0 = __fadd_rn(__fadd_rn(__fadd_rn(__fmul_rn(mp[0], r0), __fmul_rn(mp[1], r1)), __fmul_rn(mp[2], q2)), mp[18]);
    float g1 = __fadd_rn(__fadd_rn(__fadd_rn(__fmul_rn(mp[3], r0), __fmul_rn(mp[4], r1)), __fmul_rn(mp[5], q2)), mp[19]);
    float g2 = __fadd_rn(__fadd_rn(__fadd_rn(__fmul_rn(mp[6], r0), __fmul_rn(mp[7], r1)), __fmul_rn(mp[8], q2)), mp[20]);

    float s0 = __fdiv_rn(__fsub_rn(g0, -50.0f), 0.5f);
    float s1 = __fdiv_rn(__fsub_rn(g1, -50.0f), 0.5f);
    float s2 = __fdiv_rn(__fsub_rn(g2, -10.0f), 20.0f);
    s0 = fminf(fmaxf(s0, -1e6f), 1e6f);
    s1 = fminf(fmaxf(s1, -1e6f), 1e6f);
    s2 = fminf(fmaxf(s2, -1e6f), 1e6f);
    int i0 = (int)s0;   // trunc toward zero == jnp.trunc().astype(int32)
    int i1 = (int)s1;
    int i2 = (int)s2;
    if (i0 >= 0 && i0 < NX0_ && i1 >= 0 && i1 < NX1_ && i2 >= 0 && i2 < 1)
        return b * NXY + i0 * NX1_ + i1;
    return -1;
}

// One 16-lane group per (b,n,d,w) column; lane l owns channels [4l,4l+4).
// TO_WS=true: accumulate into ws laid out [B][XY][C] -> each column's 64
// channels are 256 CONTIGUOUS bytes (2 cache lines instead of 64), and the
// set of atomic-target lines collapses to ~4 MB (L2-resident) instead of
// 41 MB of scattered channel planes (round-1 diagnosis: HBM RMW line churn,
// WRITE_SIZE 70 MB > 41 MB output, avg wave lifetime ~96k cycles).
// TO_WS=false: legacy direct-to-out path (fallback if ws too small).
template <bool TO_WS>
__global__ __launch_bounds__(256) void col_pool(const float* __restrict__ x,
                                                const float* __restrict__ mats,
                                                float* __restrict__ dst) {
    int cid  = blockIdx.x * 16 + (threadIdx.x >> 4);   // NCOL = 2706*16
    int l    = threadIdx.x & 15;                       // channel quad
    int w = cid % NFW; int t = cid / NFW;
    int d = t % ND_;   t /= ND_;
    int n = t % NN_;   int b = t / NN_;

    int myidx = compute_idx(b, n, d, l, w, mats);

    // gather all 16 per-h indices into registers (no loop-carried deps)
    int idx[16];
    #pragma unroll
    for (int h = 0; h < 16; ++h) idx[h] = __shfl(myidx, h, 16);

    int common = -1;
    bool allsame = true;
    #pragma unroll
    for (int h = 0; h < 16; ++h) {
        if (idx[h] >= 0) {
            if (common < 0) common = idx[h];
            else if (idx[h] != common) allsame = false;
        }
    }
    if (common < 0) return;   // whole column dropped: skip all loads

    const float4* xp = (const float4*)
        (x + (((size_t)((b * NN_ + n) * ND_ + d) * NFH) * NFW + w) * NC) + l;
    const int HSTRIDE = NFW * (NC / 4);   // float4 stride between h rows

    // 16 independent loads — compiler can keep all in flight
    float4 v[16];
    #pragma unroll
    for (int h = 0; h < 16; ++h) v[h] = xp[h * HSTRIDE];

    if (__builtin_expect(allsame, 1)) {
        // branchless mask-multiply accumulate (== reference's feats*w)
        float4 a0 = make_float4(0.f, 0.f, 0.f, 0.f);
        float4 a1 = make_float4(0.f, 0.f, 0.f, 0.f);
        #pragma unroll
        for (int h = 0; h < 16; h += 2) {
            float m0 = (idx[h]     >= 0) ? 1.0f : 0.0f;
            float m1 = (idx[h + 1] >= 0) ? 1.0f : 0.0f;
            a0.x += v[h].x * m0;     a0.y += v[h].y * m0;
            a0.z += v[h].z * m0;     a0.w += v[h].w * m0;
            a1.x += v[h + 1].x * m1; a1.y += v[h + 1].y * m1;
            a1.z += v[h + 1].z * m1; a1.w += v[h + 1].w * m1;
        }
        a0.x += a1.x; a0.y += a1.y; a0.z += a1.z; a0.w += a1.w;
        if (TO_WS) {
            float* o = dst + (size_t)common * NC + (l << 2);  // contiguous quad
            hw_fadd(o,     a0.x);
            hw_fadd(o + 1, a0.y);
            hw_fadd(o + 2, a0.z);
            hw_fadd(o + 3, a0.w);
        } else {
            int bb = common / NXY, xy = common % NXY;
            float* o = dst + ((size_t)(bb * NC + l * 4)) * NXY + xy;
            hw_fadd(o,           a0.x);
            hw_fadd(o + NXY,     a0.y);
            hw_fadd(o + 2 * NXY, a0.z);
            hw_fadd(o + 3 * NXY, a0.w);
        }
    } else {
        // safety net (provably unreachable for these inputs)
        #pragma unroll
        for (int h = 0; h < 16; ++h) {
            if (idx[h] >= 0) {
                if (TO_WS) {
                    float* o = dst + (size_t)idx[h] * NC + (l << 2);
                    hw_fadd(o,     v[h].x);
                    hw_fadd(o + 1, v[h].y);
                    hw_fadd(o + 2, v[h].z);
                    hw_fadd(o + 3, v[h].w);
                } else {
                    int bb = idx[h] / NXY, xy = idx[h] % NXY;
                    float* o = dst + ((size_t)(bb * NC + l * 4)) * NXY + xy;
                    hw_fadd(o,           v[h].x);
                    hw_fadd(o + NXY,     v[h].y);
                    hw_fadd(o + 2 * NXY, v[h].z);
                    hw_fadd(o + 3 * NXY, v[h].w);
                }
            }
        }
    }
}

// ws [B][XY][C]  ->  out [B][C][XY].
// Tile: 64 cells x 64 channels (16 KB LDS), XOR-swizzled float4 slots so both
// the b128 LDS writes and the per-component reads are <=2-way bank aliased
// (free). Global reads AND writes are fully-coalesced float4 (per store
// instruction: 4 channel rows x 256 contiguous bytes — not the 64-line
// scatter that killed the atomic path). Writes every out element -> also
// replaces the output memset.
__global__ __launch_bounds__(256) void transpose_ws(const float* __restrict__ ws,
                                                    float* __restrict__ out) {
    __shared__ float4 tile[64 * 16];   // [cell][c4 ^ ((cell>>2)&15)]
    int b   = blockIdx.y;
    int xy0 = blockIdx.x * 64;

    const float4* src = (const float4*)(ws + ((size_t)b * NXY + xy0) * NC);
    #pragma unroll
    for (int s = 0; s < 4; ++s) {
        int f  = s * 256 + threadIdx.x;    // 0..1023 float4s
        int i  = f >> 4;                   // cell 0..63
        int c4 = f & 15;                   // channel quad 0..15
        tile[i * 16 + (c4 ^ ((i >> 2) & 15))] = src[f];
    }
    __syncthreads();

    int l  = threadIdx.x & 63;
    int wv = threadIdx.x >> 6;
    int q  = l & 15;                       // cell quad -> i0 = 4q
    int lh = l >> 4;                       // sub-channel 0..3
    int i0 = q << 2;
    #pragma unroll
    for (int s = 0; s < 4; ++s) {
        int c  = s * 16 + wv * 4 + lh;     // covers 0..63 exactly once
        int c4 = c >> 2, cr = c & 3;
        float4 v;
        v.x = ((const float*)&tile[(i0 + 0) * 16 + (c4 ^ q)])[cr];
        v.y = ((const float*)&tile[(i0 + 1) * 16 + (c4 ^ q)])[cr];
        v.z = ((const float*)&tile[(i0 + 2) * 16 + (c4 ^ q)])[cr];
        v.w = ((const float*)&tile[(i0 + 3) * 16 + (c4 ^ q)])[cr];
        *(float4*)(out + ((size_t)(b * NC + c)) * NXY + xy0 + i0) = v;
    }
}

extern "C" void kernel_launch(void* const* d_in, const int* in_sizes, int n_in,
                              void* d_out, int out_size, void* d_ws, size_t ws_size,
                              hipStream_t stream) {
    (void)in_sizes; (void)n_in; (void)out_size;
    const float* x          = (const float*)d_in[0];
    const float* rots       = (const float*)d_in[1];
    const float* trans      = (const float*)d_in[2];
    const float* intrins    = (const float*)d_in[3];
    const float* post_rots  = (const float*)d_in[4];
    const float* post_trans = (const float*)d_in[5];
    float* out = (float*)d_out;

    const size_t acc_floats = (size_t)NB * NXY * NC;            // 10,240,000
    const size_t need = (acc_floats + 1024) * sizeof(float);    // acc + mats

    if (ws_size >= need) {
        float* acc  = (float*)d_ws;
        float* mats = acc + acc_floats;
        setup_kernel<<<1, 32, 0, stream>>>(rots, trans, intrins, post_rots, post_trans, mats);
        hipMemsetAsync(acc, 0, acc_floats * sizeof(float), stream);
        col_pool<true><<<NCOL / 16, 256, 0, stream>>>(x, mats, acc);
        transpose_ws<<<dim3(NXY / 64, NB), 256, 0, stream>>>(acc, out);
    } else {
        // fallback: legacy direct-atomic path
        float* mats = (float*)d_ws;   // 576 floats
        setup_kernel<<<1, 32, 0, stream>>>(rots, trans, intrins, post_rots, post_trans, mats);
        hipMemsetAsync(out, 0, (size_t)NB * NC * NXY * sizeof(float), stream);
        col_pool<false><<<NCOL / 16, 256, 0, stream>>>(x, mats, out);
    }
}

// Round 3
// 280.543 us; speedup vs baseline: 1.1791x; 1.0195x over previous
//
#include <hip/hip_runtime.h>
#include <cstddef>

// ---------------- problem constants (match reference) ----------------
#define NB   4
#define NN_  6
#define ND_  41
#define NFH  16
#define NFW  44
#define NC   64
#define NX0_ 200
#define NX1_ 200
#define NXY  (NX0_ * NX1_)                 // 40000
#define NCOL (NB * NN_ * ND_ * NFW)        // 43296 columns (each = 16 vertical pixels)

// 3x3 inverse via adjugate. For these inputs (integer pinhole K, identity
// post_rots) every cofactor/det is exact in f32 and each division correctly
// rounded -> matches numpy's inv bit-for-bit. (Validated rounds 1-2.)
__device__ __forceinline__ void inv3(const float* a, float* inv) {
    float c00 = __fsub_rn(__fmul_rn(a[4], a[8]), __fmul_rn(a[5], a[7]));
    float c01 = __fsub_rn(__fmul_rn(a[5], a[6]), __fmul_rn(a[3], a[8]));
    float c02 = __fsub_rn(__fmul_rn(a[3], a[7]), __fmul_rn(a[4], a[6]));
    float det = __fadd_rn(__fadd_rn(__fmul_rn(a[0], c00), __fmul_rn(a[1], c01)),
                          __fmul_rn(a[2], c02));
    inv[0] = __fdiv_rn(c00, det);
    inv[1] = __fdiv_rn(__fsub_rn(__fmul_rn(a[2], a[7]), __fmul_rn(a[1], a[8])), det);
    inv[2] = __fdiv_rn(__fsub_rn(__fmul_rn(a[1], a[5]), __fmul_rn(a[2], a[4])), det);
    inv[3] = __fdiv_rn(c01, det);
    inv[4] = __fdiv_rn(__fsub_rn(__fmul_rn(a[0], a[8]), __fmul_rn(a[2], a[6])), det);
    inv[5] = __fdiv_rn(__fsub_rn(__fmul_rn(a[2], a[3]), __fmul_rn(a[0], a[5])), det);
    inv[6] = __fdiv_rn(c02, det);
    inv[7] = __fdiv_rn(__fsub_rn(__fmul_rn(a[1], a[6]), __fmul_rn(a[0], a[7])), det);
    inv[8] = __fdiv_rn(__fsub_rn(__fmul_rn(a[0], a[4]), __fmul_rn(a[1], a[3])), det);
}

__global__ void setup_kernel(const float* __restrict__ rots,
                             const float* __restrict__ trans,
                             const float* __restrict__ intrins,
                             const float* __restrict__ post_rots,
                             const float* __restrict__ post_trans,
                             float* __restrict__ mats) {
    int t = threadIdx.x;
    if (t >= NB * NN_) return;
    const float* R  = rots      + t * 9;
    const float* K  = intrins   + t * 9;
    const float* PR = post_rots + t * 9;
    float Kinv[9], Pinv[9];
    inv3(K, Kinv);
    inv3(PR, Pinv);
    float* o = mats + t * 24;
    for (int i = 0; i < 3; ++i)
        for (int k = 0; k < 3; ++k) {
            float s = __fmul_rn(R[i * 3 + 0], Kinv[0 * 3 + k]);
            s = __fadd_rn(s, __fmul_rn(R[i * 3 + 1], Kinv[1 * 3 + k]));
            s = __fadd_rn(s, __fmul_rn(R[i * 3 + 2], Kinv[2 * 3 + k]));
            o[i * 3 + k] = s;
        }
    for (int i = 0; i < 9; ++i) o[9 + i] = Pinv[i];
    o[18] = trans[t * 3 + 0];
    o[19] = trans[t * 3 + 1];
    o[20] = trans[t * 3 + 2];
    o[21] = post_trans[t * 3 + 0];
    o[22] = post_trans[t * 3 + 1];
    o[23] = post_trans[t * 3 + 2];
}

// Fire-and-forget hardware FP32 atomic add (no return value -> no CAS loop,
// no dependency on the result).
__device__ __forceinline__ void hw_fadd(float* p, float v) {
    asm volatile("global_atomic_add_f32 %0, %1, off" : : "v"(p), "v"(v) : "memory");
}

// Voxel flat index (b*NXY + i0*NX1 + i1) for point (b,n,d,h,w), or -1.
// Numerics IDENTICAL to the passing rounds: _rn intrinsics only (no fma
// contraction), f64 linspace semantics for u, trunc-toward-zero.
__device__ __forceinline__ int compute_idx(int b, int n, int d, int h, int w,
                                           const float* __restrict__ mats) {
    const float* mp = mats + (b * NN_ + n) * 24;

    float u   = (w == NFW - 1) ? 703.0f : (float)((double)w * (703.0 / 43.0));
    float v   = __fmul_rn((float)h, 17.0f);   // 255/15 == 17 exactly
    float dep = (float)(4 + d);               // arange(4,45,1): exact ints

    float f0 = __fsub_rn(u, mp[21]);
    float f1 = __fsub_rn(v, mp[22]);
    float f2 = __fsub_rn(dep, mp[23]);

    float q0 = __fadd_rn(__fadd_rn(__fmul_rn(mp[9],  f0), __fmul_rn(mp[10], f1)), __fmul_rn(mp[11], f2));
    float q1 = __fadd_rn(__fadd_rn(__fmul_rn(mp[12], f0), __fmul_rn(mp[13], f1)), __fmul_rn(mp[14], f2));
    float q2 = __fadd_rn(__fadd_rn(__fmul_rn(mp[15], f0), __fmul_rn(mp[16], f1)), __fmul_rn(mp[17], f2));

    float r0 = __fmul_rn(q0, q2);
    float r1 = __fmul_rn(q1, q2);

    float g0 = __fadd_rn(__fadd_rn(__fadd_rn(__fmul_rn(mp[0], r0), __fmul_rn(mp[1], r1)), __fmul_rn(mp[2], q2)), mp[18]);
    float g1 = __fadd_rn(__fadd_rn(__fadd_rn(__fmul_rn(mp[3], r0), __fmul_rn(mp[4], r1)), __fmul_rn(mp[5], q2)), mp[19]);
    float g2 = __fadd_rn(__fadd_rn(__fadd_rn(__fmul_rn(mp[6], r0), __fmul_rn(mp[7], r1)), __fmul_rn(mp[8], q2)), mp[20]);

    float s0 = __fdiv_rn(__fsub_rn(g0, -50.0f), 0.5f);
    float s1 = __fdiv_rn(__fsub_rn(g1, -50.0f), 0.5f);
    float s2 = __fdiv_rn(__fsub_rn(g2, -10.0f), 20.0f);
    s0 = fminf(fmaxf(s0, -1e6f), 1e6f);
    s1 = fminf(fmaxf(s1, -1e6f), 1e6f);
    s2 = fminf(fmaxf(s2, -1e6f), 1e6f);
    int i0 = (int)s0;   // trunc toward zero == jnp.trunc().astype(int32)
    int i1 = (int)s1;
    int i2 = (int)s2;
    if (i0 >= 0 && i0 < NX0_ && i1 >= 0 && i1 < NX1_ && i2 >= 0 && i2 < 1)
        return b * NXY + i0 * NX1_ + i1;
    return -1;
}

// 32 lanes per (b,n,d,w) column: lane = (hh<<4)|l, l = channel quad, hh = h
// half. Round-2 diagnosis: VGPR_Count=44 proves the old 16-deep v[16] load
// chain was serialized by the register allocator (64 VGPRs would be needed
// in-flight) -> latency-bound. Now each thread loads only 8 float4 (32 VGPR,
// all in flight) and wave count doubles (2x TLP). Partial sums combine via
// shfl_xor(16); atomic count UNCHANGED (only hh==0 lanes store).
// Lanes 16..31 compute the same compute_idx as 0..15 (h = l), so the
// column-level min/max reduce only needs a width-16 butterfly.
template <bool TO_WS>
__global__ __launch_bounds__(256) void col_pool(const float* __restrict__ x,
                                                const float* __restrict__ mats,
                                                float* __restrict__ dst) {
    int cid = blockIdx.x * 8 + (threadIdx.x >> 5);     // NCOL = 5412*8
    int sub = threadIdx.x & 31;
    int l   = sub & 15;                                // channel quad
    int hh  = sub >> 4;                                // h half: 0 -> h0..7, 1 -> h8..15
    int w = cid % NFW; int t = cid / NFW;
    int d = t % ND_;   t /= ND_;
    int n = t % NN_;   int b = t / NN_;

    int myidx = compute_idx(b, n, d, l, w, mats);      // h = l (lanes 16+ mirror 0..15)

    // column-uniform summary: min/max over valid idx (4-step butterfly, w=16)
    int vmin = (myidx >= 0) ? myidx : 0x7fffffff;
    int vmax = myidx;                                  // invalid == -1 loses max
    #pragma unroll
    for (int k = 1; k < 16; k <<= 1) {
        vmin = min(vmin, __shfl_xor(vmin, k, 16));
        vmax = max(vmax, __shfl_xor(vmax, k, 16));
    }
    if (vmax < 0) return;            // whole column dropped: skip all loads
    int  common  = vmax;
    bool allsame = (vmin == vmax) || (vmin == 0x7fffffff);

    // this thread's 8 per-h indices (hoisted above the branch so no shfl
    // executes under divergence; also provides the accumulate masks)
    int idx8[8];
    #pragma unroll
    for (int j = 0; j < 8; ++j) idx8[j] = __shfl(myidx, hh * 8 + j, 32);

    const float4* xp = (const float4*)
        (x + (((size_t)((b * NN_ + n) * ND_ + d) * NFH) * NFW + w) * NC) + l;
    const int HSTRIDE = NFW * (NC / 4);   // float4 stride between h rows

    // 8 independent loads — few enough to stay in flight at ~55 VGPR
    float4 v[8];
    #pragma unroll
    for (int j = 0; j < 8; ++j) v[j] = xp[(hh * 8 + j) * HSTRIDE];

    if (__builtin_expect(allsame, 1)) {
        // branchless mask-multiply accumulate (== reference's feats*w)
        float4 a0 = make_float4(0.f, 0.f, 0.f, 0.f);
        float4 a1 = make_float4(0.f, 0.f, 0.f, 0.f);
        #pragma unroll
        for (int j = 0; j < 8; j += 2) {
            float m0 = (idx8[j]     >= 0) ? 1.0f : 0.0f;
            float m1 = (idx8[j + 1] >= 0) ? 1.0f : 0.0f;
            a0.x += v[j].x * m0;     a0.y += v[j].y * m0;
            a0.z += v[j].z * m0;     a0.w += v[j].w * m0;
            a1.x += v[j + 1].x * m1; a1.y += v[j + 1].y * m1;
            a1.z += v[j + 1].z * m1; a1.w += v[j + 1].w * m1;
        }
        a0.x += a1.x; a0.y += a1.y; a0.z += a1.z; a0.w += a1.w;
        // combine h-halves (partner = lane ^ 16 within the 32-lane group)
        a0.x += __shfl_xor(a0.x, 16, 32);
        a0.y += __shfl_xor(a0.y, 16, 32);
        a0.z += __shfl_xor(a0.z, 16, 32);
        a0.w += __shfl_xor(a0.w, 16, 32);
        if (hh == 0) {
            if (TO_WS) {
                float* o = dst + (size_t)common * NC + (l << 2);  // contiguous quad
                hw_fadd(o,     a0.x);
                hw_fadd(o + 1, a0.y);
                hw_fadd(o + 2, a0.z);
                hw_fadd(o + 3, a0.w);
            } else {
                int bb = common / NXY, xy = common % NXY;
                float* o = dst + ((size_t)(bb * NC + l * 4)) * NXY + xy;
                hw_fadd(o,           a0.x);
                hw_fadd(o + NXY,     a0.y);
                hw_fadd(o + 2 * NXY, a0.z);
                hw_fadd(o + 3 * NXY, a0.w);
            }
        }
    } else {
        // safety net (provably unreachable for these inputs); both halves
        // handle their own h's -> no double counting
        #pragma unroll
        for (int j = 0; j < 8; ++j) {
            if (idx8[j] >= 0) {
                if (TO_WS) {
                    float* o = dst + (size_t)idx8[j] * NC + (l << 2);
                    hw_fadd(o,     v[j].x);
                    hw_fadd(o + 1, v[j].y);
                    hw_fadd(o + 2, v[j].z);
                    hw_fadd(o + 3, v[j].w);
                } else {
                    int bb = idx8[j] / NXY, xy = idx8[j] % NXY;
                    float* o = dst + ((size_t)(bb * NC + l * 4)) * NXY + xy;
                    hw_fadd(o,           v[j].x);
                    hw_fadd(o + NXY,     v[j].y);
                    hw_fadd(o + 2 * NXY, v[j].z);
                    hw_fadd(o + 3 * NXY, v[j].w);
                }
            }
        }
    }
}

// ws [B][XY][C]  ->  out [B][C][XY].  (Unchanged from round 2 — validated.)
// Tile: 64 cells x 64 channels (16 KB LDS), XOR-swizzled float4 slots so both
// the b128 LDS writes and the per-component reads are <=2-way bank aliased
// (free). Global reads AND writes are fully-coalesced float4. Writes every
// out element -> also replaces the output memset.
__global__ __launch_bounds__(256) void transpose_ws(const float* __restrict__ ws,
                                                    float* __restrict__ out) {
    __shared__ float4 tile[64 * 16];   // [cell][c4 ^ ((cell>>2)&15)]
    int b   = blockIdx.y;
    int xy0 = blockIdx.x * 64;

    const float4* src = (const float4*)(ws + ((size_t)b * NXY + xy0) * NC);
    #pragma unroll
    for (int s = 0; s < 4; ++s) {
        int f  = s * 256 + threadIdx.x;    // 0..1023 float4s
        int i  = f >> 4;                   // cell 0..63
        int c4 = f & 15;                   // channel quad 0..15
        tile[i * 16 + (c4 ^ ((i >> 2) & 15))] = src[f];
    }
    __syncthreads();

    int l  = threadIdx.x & 63;
    int wv = threadIdx.x >> 6;
    int q  = l & 15;                       // cell quad -> i0 = 4q
    int lh = l >> 4;                       // sub-channel 0..3
    int i0 = q << 2;
    #pragma unroll
    for (int s = 0; s < 4; ++s) {
        int c  = s * 16 + wv * 4 + lh;     // covers 0..63 exactly once
        int c4 = c >> 2, cr = c & 3;
        float4 v;
        v.x = ((const float*)&tile[(i0 + 0) * 16 + (c4 ^ q)])[cr];
        v.y = ((const float*)&tile[(i0 + 1) * 16 + (c4 ^ q)])[cr];
        v.z = ((const float*)&tile[(i0 + 2) * 16 + (c4 ^ q)])[cr];
        v.w = ((const float*)&tile[(i0 + 3) * 16 + (c4 ^ q)])[cr];
        *(float4*)(out + ((size_t)(b * NC + c)) * NXY + xy0 + i0) = v;
    }
}

extern "C" void kernel_launch(void* const* d_in, const int* in_sizes, int n_in,
                              void* d_out, int out_size, void* d_ws, size_t ws_size,
                              hipStream_t stream) {
    (void)in_sizes; (void)n_in; (void)out_size;
    const float* x          = (const float*)d_in[0];
    const float* rots       = (const float*)d_in[1];
    const float* trans      = (const float*)d_in[2];
    const float* intrins    = (const float*)d_in[3];
    const float* post_rots  = (const float*)d_in[4];
    const float* post_trans = (const float*)d_in[5];
    float* out = (float*)d_out;

    const size_t acc_floats = (size_t)NB * NXY * NC;            // 10,240,000
    const size_t need = (acc_floats + 1024) * sizeof(float);    // acc + mats

    if (ws_size >= need) {
        float* acc  = (float*)d_ws;
        float* mats = acc + acc_floats;
        setup_kernel<<<1, 32, 0, stream>>>(rots, trans, intrins, post_rots, post_trans, mats);
        hipMemsetAsync(acc, 0, acc_floats * sizeof(float), stream);
        col_pool<true><<<NCOL / 8, 256, 0, stream>>>(x, mats, acc);
        transpose_ws<<<dim3(NXY / 64, NB), 256, 0, stream>>>(acc, out);
    } else {
        // fallback: legacy direct-atomic path
        float* mats = (float*)d_ws;   // 576 floats
        setup_kernel<<<1, 32, 0, stream>>>(rots, trans, intrins, post_rots, post_trans, mats);
        hipMemsetAsync(out, 0, (size_t)NB * NC * NXY * sizeof(float), stream);
        col_pool<false><<<NCOL / 8, 256, 0, stream>>>(x, mats, out);
    }
}